// Round 2
// baseline (390.181 us; speedup 1.0000x reference)
//
#include <hip/hip_runtime.h>
#include <hip/hip_bf16.h>

// SpatialAttention: out[b,i,j] = softmax_j( sum_c w3[c] * tanh(x1[b,i,c] + x2[b,j,c]) )
// where x1 = x@W1^T, x2 = x@W2^T.  B=4, N=1024, C=64.
//
// tanh(x) = 1 - 2/(e^{2x}+1).  Pre-scale projections by K2 = 2*log2(e) so
// t = exp2(x1' + x2'), fold the "1 - 2r" + w3 weighting:
//   att = sum(w3) - 2 * sum_c w3[c] * rcp(exp2(y_c) + 1)
// Per element: v_add, v_exp_f32 (1/4-rate), v_add, v_rcp_f32 (1/4-rate), v_fma.
// No clamp needed: exp2(+big)=inf -> rcp(inf)=0 (tanh->1), exp2(-big)=0 ->
// rcp(1)=1 (tanh->-1) — IEEE gives the exact limits.
//
// R1 fix: R0 spilled the per-thread x2' row to scratch (VGPR_Count=64,
// 296 MB WRITE_SIZE).  float4 xv[16] with constant indices + waves_per_eu(4,4)
// (128-VGPR budget) keeps the row in registers.

#define BATCH 4
#define NN    1024
#define CC    64
#define TI    4      // rows i per block
#define BLK   256
#define NCH   (NN / BLK)   // 4 j-chunks

__device__ __forceinline__ float fast_exp2(float x) {
#if __has_builtin(__builtin_amdgcn_exp2f)
    return __builtin_amdgcn_exp2f(x);
#else
    return exp2f(x);
#endif
}
__device__ __forceinline__ float fast_rcp(float x) {
#if __has_builtin(__builtin_amdgcn_rcpf)
    return __builtin_amdgcn_rcpf(x);
#else
    return 1.0f / x;
#endif
}

// ---------------- Kernel 1: projections, pre-scaled by 2*log2(e) ------------
__global__ __launch_bounds__(256) void proj_kernel(
    const float* __restrict__ x, const float* __restrict__ W1,
    const float* __restrict__ W2, float* __restrict__ x1p,
    float* __restrict__ x2p) {
    const int w    = threadIdx.x >> 6;
    const int lane = threadIdx.x & 63;
    const int r    = blockIdx.x * 4 + w;   // grid = 1024 -> r < 4096
    const float4* __restrict__ xrow  = (const float4*)(x  + (size_t)r    * CC);
    const float4* __restrict__ w1row = (const float4*)(W1 + (size_t)lane * CC);
    const float4* __restrict__ w2row = (const float4*)(W2 + (size_t)lane * CC);
    float a1 = 0.f, a2 = 0.f;
#pragma unroll
    for (int q = 0; q < 16; ++q) {
        float4 xv = xrow[q];
        float4 u  = w1row[q];
        float4 v  = w2row[q];
        a1 = fmaf(xv.x, u.x, a1); a1 = fmaf(xv.y, u.y, a1);
        a1 = fmaf(xv.z, u.z, a1); a1 = fmaf(xv.w, u.w, a1);
        a2 = fmaf(xv.x, v.x, a2); a2 = fmaf(xv.y, v.y, a2);
        a2 = fmaf(xv.z, v.z, a2); a2 = fmaf(xv.w, v.w, a2);
    }
    const float K2 = 2.8853900817779268f;  // 2*log2(e)
    x1p[(size_t)r * CC + lane] = a1 * K2;
    x2p[(size_t)r * CC + lane] = a2 * K2;
}

// ---------------- Kernel 2: fused att + softmax -----------------------------
__global__ __attribute__((amdgpu_waves_per_eu(4, 4))) __launch_bounds__(BLK)
void attn_kernel(
    const float* __restrict__ x1p, const float* __restrict__ x2p,
    const float* __restrict__ w3, float* __restrict__ out) {
    __shared__ float x1t[CC * TI];          // [c][i] transposed: 1 KB
    __shared__ float w3s[CC];
    __shared__ float att_lds[TI * NN];      // 16 KB

    const int tid = threadIdx.x;
    const int bi  = blockIdx.x;             // 1024 blocks
    const int b   = bi >> 8;                // N/TI = 256 blocks per batch
    const int i0  = (bi & 255) * TI;

    // stage x1' tile transposed + w3
    {
        const int ii = tid >> 6, c = tid & 63;
        x1t[c * TI + ii] = x1p[(size_t)((b << 10) + i0 + ii) * CC + c];
        if (tid < CC) w3s[tid] = w3[tid];
    }
    __syncthreads();

    float sumw3 = 0.f;
#pragma unroll
    for (int c = 0; c < CC; ++c) sumw3 += w3s[c];

    const float4* __restrict__ x2r =
        (const float4*)(x2p + ((size_t)b << 10) * CC);
    const float4* x1t4 = (const float4*)x1t;      // [c] -> 4 i's
    const float4* w3s4 = (const float4*)w3s;

    for (int ch = 0; ch < NCH; ++ch) {
        const int j = ch * BLK + tid;
        const float4* __restrict__ xrow = x2r + (size_t)j * 16;

        float4 xv[16];                      // whole x2' row: 64 VGPRs (SROA)
#pragma unroll
        for (int q = 0; q < 16; ++q) xv[q] = xrow[q];

        float acc0 = 0.f, acc1 = 0.f, acc2 = 0.f, acc3 = 0.f;
        auto step = [&](const float4 a, const float xc, const float wc) {
            acc0 = fmaf(wc, fast_rcp(fast_exp2(a.x + xc) + 1.f), acc0);
            acc1 = fmaf(wc, fast_rcp(fast_exp2(a.y + xc) + 1.f), acc1);
            acc2 = fmaf(wc, fast_rcp(fast_exp2(a.z + xc) + 1.f), acc2);
            acc3 = fmaf(wc, fast_rcp(fast_exp2(a.w + xc) + 1.f), acc3);
        };
#pragma unroll
        for (int q = 0; q < 16; ++q) {
            const float4 w3q = w3s4[q];     // LDS broadcast
            step(x1t4[4 * q + 0], xv[q].x, w3q.x);
            step(x1t4[4 * q + 1], xv[q].y, w3q.y);
            step(x1t4[4 * q + 2], xv[q].z, w3q.z);
            step(x1t4[4 * q + 3], xv[q].w, w3q.w);
        }
        // att = sum(w3) - 2*acc
        att_lds[0 * NN + j] = fmaf(-2.f, acc0, sumw3);
        att_lds[1 * NN + j] = fmaf(-2.f, acc1, sumw3);
        att_lds[2 * NN + j] = fmaf(-2.f, acc2, sumw3);
        att_lds[3 * NN + j] = fmaf(-2.f, acc3, sumw3);
    }
    __syncthreads();

    // epilogue: wave w softmaxes row i0+w over j
    {
        const int w    = tid >> 6;
        const int lane = tid & 63;
        float v[16];
        float m = -3.4e38f;
#pragma unroll
        for (int k = 0; k < 16; ++k) {
            v[k] = att_lds[w * NN + k * 64 + lane];
            m = fmaxf(m, v[k]);
        }
#pragma unroll
        for (int off = 32; off >= 1; off >>= 1)
            m = fmaxf(m, __shfl_xor(m, off));
        const float L2E = 1.4426950408889634f;
        float s = 0.f;
#pragma unroll
        for (int k = 0; k < 16; ++k) {
            v[k] = fast_exp2((v[k] - m) * L2E);
            s += v[k];
        }
#pragma unroll
        for (int off = 32; off >= 1; off >>= 1)
            s += __shfl_xor(s, off);
        const float rs = fast_rcp(s);
        float* __restrict__ orow = out + (((size_t)(b << 10) + (i0 + w)) << 10);
#pragma unroll
        for (int k = 0; k < 16; ++k) orow[k * 64 + lane] = v[k] * rs;
    }
}

extern "C" void kernel_launch(void* const* d_in, const int* in_sizes, int n_in,
                              void* d_out, int out_size, void* d_ws, size_t ws_size,
                              hipStream_t stream) {
    const float* x  = (const float*)d_in[0];
    const float* W1 = (const float*)d_in[1];
    const float* W2 = (const float*)d_in[2];
    const float* w3 = (const float*)d_in[3];
    float* outp = (float*)d_out;

    float* x1p = (float*)d_ws;                       // 4096*64 fp32 = 1 MB
    float* x2p = x1p + (size_t)BATCH * NN * CC;      // second 1 MB

    proj_kernel<<<dim3(BATCH * NN / 4), dim3(256), 0, stream>>>(x, W1, W2, x1p, x2p);
    attn_kernel<<<dim3(BATCH * NN / TI), dim3(BLK), 0, stream>>>(x1p, x2p, w3, outp);
}

// Round 3
// 115.646 us; speedup vs baseline: 3.3739x; 3.3739x over previous
//
#include <hip/hip_runtime.h>
#include <hip/hip_bf16.h>

// SpatialAttention: out[b,i,j] = softmax_j( sum_c w3[c] * tanh(x1[b,i,c] + x2[b,j,c]) )
// x1 = x@W1^T, x2 = x@W2^T.  B=4, N=1024, C=64.
//
// tanh(s) = 1 - 2/(e^{2s}+1) = 1 - 2/(exp2(K2*s)+1), K2 = 2*log2(e).
// Key factorization: exp2(K2*(x1+x2)) = e1 * e2 with e1,e2 PRECOMPUTED in the
// proj kernel (512K exp2s) — the 268M-element inner loop is then just
//   d = fma(e1, e2, 1);  acc = fma(w3c, rcp(d), acc)     (2 full + 1 trans op)
// att = sum(w3) - 2*acc.  e1,e2 clamped to 2^15 so t <= 2^30: no inf/NaN,
// tanh saturation error <= 2e-9.
//
// R2 fix: R0/R1 spilled the 64-float per-thread x2 row (VGPR_Count=64,
// ~290 MB scratch WRITE).  The c-loop is now tiled (#pragma unroll 1 over
// 4 tiles of 16 c) so live state is ~48 VGPRs — fits the 64-VGPR budget.

#define BATCH 4
#define NN    1024
#define CC    64
#define TI    4      // rows i per block
#define BLK   256
#define NCH   (NN / BLK)   // 4 j-chunks

__device__ __forceinline__ float fast_exp2(float x) {
#if __has_builtin(__builtin_amdgcn_exp2f)
    return __builtin_amdgcn_exp2f(x);
#else
    return exp2f(x);
#endif
}
__device__ __forceinline__ float fast_rcp(float x) {
#if __has_builtin(__builtin_amdgcn_rcpf)
    return __builtin_amdgcn_rcpf(x);
#else
    return 1.0f / x;
#endif
}

// ---------------- Kernel 1: projections -> exp2 factors ---------------------
// e1[r,d] = exp2(min(K2 * (x[r,:]·W1[d,:]), 15)),  e2 likewise with W2.
__global__ __launch_bounds__(256) void proj_kernel(
    const float* __restrict__ x, const float* __restrict__ W1,
    const float* __restrict__ W2, float* __restrict__ e1p,
    float* __restrict__ e2p) {
    const int w    = threadIdx.x >> 6;
    const int lane = threadIdx.x & 63;
    const int r    = blockIdx.x * 4 + w;   // grid = 1024 -> r < 4096
    const float4* __restrict__ xrow  = (const float4*)(x  + (size_t)r    * CC);
    const float4* __restrict__ w1row = (const float4*)(W1 + (size_t)lane * CC);
    const float4* __restrict__ w2row = (const float4*)(W2 + (size_t)lane * CC);
    float a1 = 0.f, a2 = 0.f;
#pragma unroll
    for (int q = 0; q < 16; ++q) {
        float4 xv = xrow[q];
        float4 u  = w1row[q];
        float4 v  = w2row[q];
        a1 = fmaf(xv.x, u.x, a1); a1 = fmaf(xv.y, u.y, a1);
        a1 = fmaf(xv.z, u.z, a1); a1 = fmaf(xv.w, u.w, a1);
        a2 = fmaf(xv.x, v.x, a2); a2 = fmaf(xv.y, v.y, a2);
        a2 = fmaf(xv.z, v.z, a2); a2 = fmaf(xv.w, v.w, a2);
    }
    const float K2 = 2.8853900817779268f;  // 2*log2(e)
    e1p[(size_t)r * CC + lane] = fast_exp2(fminf(a1 * K2, 15.f));
    e2p[(size_t)r * CC + lane] = fast_exp2(fminf(a2 * K2, 15.f));
}

// ---------------- Kernel 2: fused att + softmax -----------------------------
__global__ __launch_bounds__(BLK) void attn_kernel(
    const float* __restrict__ e1p, const float* __restrict__ e2p,
    const float* __restrict__ w3, float* __restrict__ out) {
    __shared__ float e1t[CC * TI];          // [c][i] transposed: 1 KB
    __shared__ float w3s[CC];
    __shared__ float att_lds[TI * NN];      // 16 KB

    const int tid = threadIdx.x;
    const int bi  = blockIdx.x;             // 1024 blocks
    const int b   = bi >> 8;                // 256 blocks per batch
    const int i0  = (bi & 255) * TI;

    // stage e1 tile transposed + w3
    {
        const int ii = tid >> 6, c = tid & 63;
        e1t[c * TI + ii] = e1p[(size_t)((b << 10) + i0 + ii) * CC + c];
        if (tid < CC) w3s[tid] = w3[tid];
    }
    __syncthreads();

    float sumw3 = 0.f;
#pragma unroll
    for (int c = 0; c < CC; ++c) sumw3 += w3s[c];

    const float4* __restrict__ e2r =
        (const float4*)(e2p + ((size_t)b << 10) * CC);
    const float4* e1t4 = (const float4*)e1t;      // [c] -> 4 i's
    const float4* w3s4 = (const float4*)w3s;

    for (int ch = 0; ch < NCH; ++ch) {
        const int j = ch * BLK + tid;
        const float4* __restrict__ row = e2r + (size_t)j * 16;

        float acc0 = 0.f, acc1 = 0.f, acc2 = 0.f, acc3 = 0.f;
        auto step = [&](const float4 a, const float ec, const float wc) {
            acc0 = fmaf(wc, fast_rcp(fmaf(a.x, ec, 1.f)), acc0);
            acc1 = fmaf(wc, fast_rcp(fmaf(a.y, ec, 1.f)), acc1);
            acc2 = fmaf(wc, fast_rcp(fmaf(a.z, ec, 1.f)), acc2);
            acc3 = fmaf(wc, fast_rcp(fmaf(a.w, ec, 1.f)), acc3);
        };
        // c-tiled: 4 tiles x 16 c.  unroll 1 keeps e2 live state at 16 regs.
#pragma unroll 1
        for (int ct = 0; ct < 4; ++ct) {
            float4 e2q0 = row[ct * 4 + 0];
            float4 e2q1 = row[ct * 4 + 1];
            float4 e2q2 = row[ct * 4 + 2];
            float4 e2q3 = row[ct * 4 + 3];
            const int q0 = ct * 4;
            float4 wq0 = w3s4[q0 + 0], wq1 = w3s4[q0 + 1];
            float4 wq2 = w3s4[q0 + 2], wq3 = w3s4[q0 + 3];
            step(e1t4[4 * (q0 + 0) + 0], e2q0.x, wq0.x);
            step(e1t4[4 * (q0 + 0) + 1], e2q0.y, wq0.y);
            step(e1t4[4 * (q0 + 0) + 2], e2q0.z, wq0.z);
            step(e1t4[4 * (q0 + 0) + 3], e2q0.w, wq0.w);
            step(e1t4[4 * (q0 + 1) + 0], e2q1.x, wq1.x);
            step(e1t4[4 * (q0 + 1) + 1], e2q1.y, wq1.y);
            step(e1t4[4 * (q0 + 1) + 2], e2q1.z, wq1.z);
            step(e1t4[4 * (q0 + 1) + 3], e2q1.w, wq1.w);
            step(e1t4[4 * (q0 + 2) + 0], e2q2.x, wq2.x);
            step(e1t4[4 * (q0 + 2) + 1], e2q2.y, wq2.y);
            step(e1t4[4 * (q0 + 2) + 2], e2q2.z, wq2.z);
            step(e1t4[4 * (q0 + 2) + 3], e2q2.w, wq2.w);
            step(e1t4[4 * (q0 + 3) + 0], e2q3.x, wq3.x);
            step(e1t4[4 * (q0 + 3) + 1], e2q3.y, wq3.y);
            step(e1t4[4 * (q0 + 3) + 2], e2q3.z, wq3.z);
            step(e1t4[4 * (q0 + 3) + 3], e2q3.w, wq3.w);
        }
        // att = sum(w3) - 2*acc
        att_lds[0 * NN + j] = fmaf(-2.f, acc0, sumw3);
        att_lds[1 * NN + j] = fmaf(-2.f, acc1, sumw3);
        att_lds[2 * NN + j] = fmaf(-2.f, acc2, sumw3);
        att_lds[3 * NN + j] = fmaf(-2.f, acc3, sumw3);
    }
    __syncthreads();

    // epilogue: wave w softmaxes row i0+w over j
    {
        const int w    = tid >> 6;
        const int lane = tid & 63;
        float v[16];
        float m = -3.4e38f;
#pragma unroll
        for (int k = 0; k < 16; ++k) {
            v[k] = att_lds[w * NN + k * 64 + lane];
            m = fmaxf(m, v[k]);
        }
#pragma unroll
        for (int off = 32; off >= 1; off >>= 1)
            m = fmaxf(m, __shfl_xor(m, off));
        const float L2E = 1.4426950408889634f;
        float s = 0.f;
#pragma unroll
        for (int k = 0; k < 16; ++k) {
            v[k] = fast_exp2((v[k] - m) * L2E);
            s += v[k];
        }
#pragma unroll
        for (int off = 32; off >= 1; off >>= 1)
            s += __shfl_xor(s, off);
        const float rs = fast_rcp(s);
        float* __restrict__ orow = out + (((size_t)(b << 10) + (i0 + w)) << 10);
#pragma unroll
        for (int k = 0; k < 16; ++k) orow[k * 64 + lane] = v[k] * rs;
    }
}

extern "C" void kernel_launch(void* const* d_in, const int* in_sizes, int n_in,
                              void* d_out, int out_size, void* d_ws, size_t ws_size,
                              hipStream_t stream) {
    const float* x  = (const float*)d_in[0];
    const float* W1 = (const float*)d_in[1];
    const float* W2 = (const float*)d_in[2];
    const float* w3 = (const float*)d_in[3];
    float* outp = (float*)d_out;

    float* e1p = (float*)d_ws;                       // 4096*64 fp32 = 1 MB
    float* e2p = e1p + (size_t)BATCH * NN * CC;      // second 1 MB

    proj_kernel<<<dim3(BATCH * NN / 4), dim3(256), 0, stream>>>(x, W1, W2, e1p, e2p);
    attn_kernel<<<dim3(BATCH * NN / TI), dim3(BLK), 0, stream>>>(e1p, e2p, w3, outp);
}

// Round 4
// 104.449 us; speedup vs baseline: 3.7356x; 1.1072x over previous
//
#include <hip/hip_runtime.h>
#include <hip/hip_bf16.h>

// SpatialAttention: out[b,i,j] = softmax_j( sum_c w3[c] * tanh(x1[b,i,c] + x2[b,j,c]) )
// x1 = x@W1^T, x2 = x@W2^T.  B=4, N=1024, C=64.
//
// tanh(s) = 1 - 2/(exp2(K2*s)+1), K2 = 2*log2(e); exp2 factorizes:
// exp2(K2*(x1+x2)) = e1*e2 precomputed in proj (clamped to 2^15 each).
// att = sum(w3) - 2 * sum_c w3[c] * rcp(fma(e1,e2,1)).
//
// R4: (1) paired reciprocal across the i-pair: r = rcp(da*db), 1/da = db*r,
//     1/db = da*r  (da,db in [1,2^30+1], product <= 2^60 — safe; ~2 ulp).
//     Halves the trans-pipe work: 268M -> 134M rcps (floor 13.7 -> 6.8 us).
// (2) w3 via uniform s_load (no LDS stream), 2 j per thread for ILP.
// (3) proj: W1/W2 staged TRANSPOSED in LDS (pitch 65, conflict-free) —
//     kills the 64-lines-per-instruction strided W loads; x rows wave-uniform.

#define BATCH 4
#define NN    1024
#define CC    64
#define TI    4              // rows i per block
#define BLK   256
#define J2    2              // j's per thread
#define NCH   (NN / (BLK * J2))   // 2 chunks
#define PP    65             // padded pitch for transposed W in LDS

__device__ __forceinline__ float fast_exp2(float x) {
#if __has_builtin(__builtin_amdgcn_exp2f)
    return __builtin_amdgcn_exp2f(x);
#else
    return exp2f(x);
#endif
}
__device__ __forceinline__ float fast_rcp(float x) {
#if __has_builtin(__builtin_amdgcn_rcpf)
    return __builtin_amdgcn_rcpf(x);
#else
    return 1.0f / x;
#endif
}

// ---------------- Kernel 1: projections -> exp2 factors ---------------------
__global__ __launch_bounds__(256) void proj_kernel(
    const float* __restrict__ x, const float* __restrict__ W1,
    const float* __restrict__ W2, float* __restrict__ e1p,
    float* __restrict__ e2p) {
    __shared__ float w1t[CC * PP];   // [c][d] transposed, 16.25 KB each
    __shared__ float w2t[CC * PP];

    const int tid = threadIdx.x;
    {   // coalesced load + transpose into LDS
        const float4* __restrict__ W1v = (const float4*)W1;
        const float4* __restrict__ W2v = (const float4*)W2;
#pragma unroll
        for (int k = 0; k < 4; ++k) {
            const int fi = k * 256 + tid;      // float4 index in [0,1024)
            const int r  = fi >> 4;            // row d
            const int c4 = (fi & 15) * 4;      // col c base
            float4 a = W1v[fi], b = W2v[fi];
            w1t[(c4 + 0) * PP + r] = a.x; w1t[(c4 + 1) * PP + r] = a.y;
            w1t[(c4 + 2) * PP + r] = a.z; w1t[(c4 + 3) * PP + r] = a.w;
            w2t[(c4 + 0) * PP + r] = b.x; w2t[(c4 + 1) * PP + r] = b.y;
            w2t[(c4 + 2) * PP + r] = b.z; w2t[(c4 + 3) * PP + r] = b.w;
        }
    }
    __syncthreads();

    const int w    = tid >> 6;
    const int lane = tid & 63;
    const int r    = blockIdx.x * 4 + w;       // wave-uniform row
    const float4* __restrict__ xr = (const float4*)(x + (size_t)r * CC);

    float a1 = 0.f, a2 = 0.f;
#pragma unroll
    for (int q = 0; q < 16; ++q) {
        const float4 xv = xr[q];               // wave-uniform -> s_load
        const float xc[4] = {xv.x, xv.y, xv.z, xv.w};
#pragma unroll
        for (int m = 0; m < 4; ++m) {
            const int c = 4 * q + m;
            a1 = fmaf(xc[m], w1t[c * PP + lane], a1);
            a2 = fmaf(xc[m], w2t[c * PP + lane], a2);
        }
    }
    const float K2 = 2.8853900817779268f;      // 2*log2(e)
    e1p[(size_t)r * CC + lane] = fast_exp2(fminf(a1 * K2, 15.f));
    e2p[(size_t)r * CC + lane] = fast_exp2(fminf(a2 * K2, 15.f));
}

// ---------------- Kernel 2: fused att + softmax -----------------------------
// paired reciprocal for one i-pair (2 elements), one j:
__device__ __forceinline__ void step2(float e1a, float e1b, float e2,
                                      float wc, float2& acc) {
    float da = fmaf(e1a, e2, 1.f);
    float db = fmaf(e1b, e2, 1.f);
    float r  = fast_rcp(da * db);
    acc.x = fmaf(wc * db, r, acc.x);   // w3c / da
    acc.y = fmaf(wc * da, r, acc.y);   // w3c / db
}

__global__ __launch_bounds__(BLK) void attn_kernel(
    const float* __restrict__ e1p, const float* __restrict__ e2p,
    const float* __restrict__ w3, float* __restrict__ out) {
    __shared__ float e1t[CC * TI];          // [c][i] transposed: 1 KB
    __shared__ float att_lds[TI * NN];      // 16 KB

    const int tid = threadIdx.x;
    const int bi  = blockIdx.x;             // 1024 blocks
    const int b   = bi >> 8;                // 256 blocks per batch
    const int i0  = (bi & 255) * TI;

    {   // stage e1 tile transposed
        const int ii = tid >> 6, c = tid & 63;
        e1t[c * TI + ii] = e1p[(size_t)((b << 10) + i0 + ii) * CC + c];
    }
    __syncthreads();

    // w3: uniform address -> scalar loads; also its sum
    const float4* __restrict__ w3q = (const float4*)w3;
    float sumw3 = 0.f;
#pragma unroll
    for (int q = 0; q < 16; ++q) {
        float4 t = w3q[q];
        sumw3 += (t.x + t.y) + (t.z + t.w);
    }

    const float* __restrict__ e2b = e2p + ((size_t)b << 10) * CC;
    const float4* e1t4 = (const float4*)e1t;   // [c] -> 4 i's (broadcast)

#pragma unroll 1
    for (int ch = 0; ch < NCH; ++ch) {
        const int j0 = ch * (BLK * J2) + tid;          // j1 = j0 + BLK
        const float4* __restrict__ rowA = (const float4*)(e2b + (size_t)j0 * CC);
        const float4* __restrict__ rowB = rowA + (BLK * CC / 4);

        float2 accA0 = {0.f, 0.f}, accA1 = {0.f, 0.f};   // j0: i01, i23
        float2 accB0 = {0.f, 0.f}, accB1 = {0.f, 0.f};   // j1: i01, i23

#pragma unroll 1
        for (int ct = 0; ct < 4; ++ct) {               // 4 c-tiles of 16
#pragma unroll
            for (int q = 0; q < 4; ++q) {
                const float4 eAv = rowA[ct * 4 + q];
                const float4 eBv = rowB[ct * 4 + q];
                const float4 wv  = w3q[ct * 4 + q];    // s_load (uniform)
                const float eAa[4] = {eAv.x, eAv.y, eAv.z, eAv.w};
                const float eBa[4] = {eBv.x, eBv.y, eBv.z, eBv.w};
                const float wa[4]  = {wv.x, wv.y, wv.z, wv.w};
#pragma unroll
                for (int m = 0; m < 4; ++m) {
                    const int c = ct * 16 + q * 4 + m;
                    const float4 ev = e1t4[c];         // LDS broadcast
                    step2(ev.x, ev.y, eAa[m], wa[m], accA0);
                    step2(ev.z, ev.w, eAa[m], wa[m], accA1);
                    step2(ev.x, ev.y, eBa[m], wa[m], accB0);
                    step2(ev.z, ev.w, eBa[m], wa[m], accB1);
                }
            }
        }
        const int j1 = j0 + BLK;
        att_lds[0 * NN + j0] = fmaf(-2.f, accA0.x, sumw3);
        att_lds[1 * NN + j0] = fmaf(-2.f, accA0.y, sumw3);
        att_lds[2 * NN + j0] = fmaf(-2.f, accA1.x, sumw3);
        att_lds[3 * NN + j0] = fmaf(-2.f, accA1.y, sumw3);
        att_lds[0 * NN + j1] = fmaf(-2.f, accB0.x, sumw3);
        att_lds[1 * NN + j1] = fmaf(-2.f, accB0.y, sumw3);
        att_lds[2 * NN + j1] = fmaf(-2.f, accB1.x, sumw3);
        att_lds[3 * NN + j1] = fmaf(-2.f, accB1.y, sumw3);
    }
    __syncthreads();

    // epilogue: wave w softmaxes row i0+w over j
    {
        const int w    = tid >> 6;
        const int lane = tid & 63;
        float v[16];
        float m = -3.4e38f;
#pragma unroll
        for (int k = 0; k < 16; ++k) {
            v[k] = att_lds[w * NN + k * 64 + lane];
            m = fmaxf(m, v[k]);
        }
#pragma unroll
        for (int off = 32; off >= 1; off >>= 1)
            m = fmaxf(m, __shfl_xor(m, off));
        const float L2E = 1.4426950408889634f;
        float s = 0.f;
#pragma unroll
        for (int k = 0; k < 16; ++k) {
            v[k] = fast_exp2((v[k] - m) * L2E);
            s += v[k];
        }
#pragma unroll
        for (int off = 32; off >= 1; off >>= 1)
            s += __shfl_xor(s, off);
        const float rs = fast_rcp(s);
        float* __restrict__ orow = out + (((size_t)(b << 10) + (i0 + w)) << 10);
#pragma unroll
        for (int k = 0; k < 16; ++k) orow[k * 64 + lane] = v[k] * rs;
    }
}

extern "C" void kernel_launch(void* const* d_in, const int* in_sizes, int n_in,
                              void* d_out, int out_size, void* d_ws, size_t ws_size,
                              hipStream_t stream) {
    const float* x  = (const float*)d_in[0];
    const float* W1 = (const float*)d_in[1];
    const float* W2 = (const float*)d_in[2];
    const float* w3 = (const float*)d_in[3];
    float* outp = (float*)d_out;

    float* e1p = (float*)d_ws;                       // 4096*64 fp32 = 1 MB
    float* e2p = e1p + (size_t)BATCH * NN * CC;      // second 1 MB

    proj_kernel<<<dim3(BATCH * NN / 4), dim3(256), 0, stream>>>(x, W1, W2, e1p, e2p);
    attn_kernel<<<dim3(BATCH * NN / TI), dim3(BLK), 0, stream>>>(e1p, e2p, w3, outp);
}